// Round 17
// baseline (226.446 us; speedup 1.0000x reference)
//
#include <hip/hip_runtime.h>

#define N_NODES 50000
#define N_EDGES 800000
#define N_GRAPHS 1024
#define N_LAYERS 5
#define D_IN 32
#define D_HID 128

#define NBUCK 256
#define BUCK_NODES 196   // ceil(N_NODES/NBUCK)
#define BUCK_REG 8192    // padded slots per bucket (mean ~3125, clamp-guarded)
#define CHUNK 4096
#define NCHUNKS ((N_EDGES + CHUNK - 1) / CHUNK)   // 196
#define EMBED_BLOCKS ((N_NODES + 63) / 64)        // 782
#define PACKW_BLOCKS ((N_LAYERS * 16384 + 255) / 256)  // 320
#define GOFF_BLOCKS ((N_GRAPHS + 1 + 255) / 256)  // 5
#define NM_BLOCKS (N_NODES / 16)                  // 3125
#define POOL_BLOCKS (N_GRAPHS / 8)                // 128

typedef __attribute__((ext_vector_type(8))) short bf16x8;
typedef __attribute__((ext_vector_type(4))) float f32x4;

// ---------------- bf16 helpers ----------------

__device__ __forceinline__ float bf_lo(unsigned u) { return __uint_as_float(u << 16); }
__device__ __forceinline__ float bf_hi(unsigned u) { return __uint_as_float(u & 0xffff0000u); }
__device__ __forceinline__ unsigned bf16_rn(float f) {
  unsigned u = __float_as_uint(f);
  return (u + 0x7fffu + ((u >> 16) & 1u)) >> 16;  // round-to-nearest-even
}
__device__ __forceinline__ unsigned pack_bf16(float a, float b) {
  return bf16_rn(a) | (bf16_rn(b) << 16);
}

// single-feature graph pool: 8 graphs/block, 32 threads/graph (4 cols each)
__device__ __forceinline__ void pool_one(const unsigned short* __restrict__ h,
                                         const int* __restrict__ goff,
                                         float* __restrict__ out,
                                         int lslice, int pb, int tid) {
  const int g = pb * 8 + (tid >> 5);
  const int t = tid & 31;
  if (g >= N_GRAPHS) return;
  const int n0 = goff[g], n1 = goff[g + 1];
  float4 s = {0.f, 0.f, 0.f, 0.f};
  int n = n0;
  for (; n + 1 < n1; n += 2) {
    uint2 v = *reinterpret_cast<const uint2*>(h + (size_t)n * D_HID + t * 4);
    uint2 w = *reinterpret_cast<const uint2*>(h + (size_t)(n + 1) * D_HID + t * 4);
    s.x += bf_lo(v.x) + bf_lo(w.x); s.y += bf_hi(v.x) + bf_hi(w.x);
    s.z += bf_lo(v.y) + bf_lo(w.y); s.w += bf_hi(v.y) + bf_hi(w.y);
  }
  if (n < n1) {
    uint2 v = *reinterpret_cast<const uint2*>(h + (size_t)n * D_HID + t * 4);
    s.x += bf_lo(v.x); s.y += bf_hi(v.x); s.z += bf_lo(v.y); s.w += bf_hi(v.y);
  }
  *reinterpret_cast<float4*>(out + (size_t)g * ((N_LAYERS + 1) * D_HID) + lslice + t * 4) = s;
}

// ---------------- fused: bucket scatter (blocks 0..NCHUNKS-1) + embed (rest) ----------------
// aux entry: (dst_local << 17) | src  (dst_local < 196 < 2^8, src < 50000 < 2^17)

__global__ __launch_bounds__(256) void scatter_embed_kernel(const int* __restrict__ src,
                                                            const int* __restrict__ dst,
                                                            int* __restrict__ gcur,
                                                            unsigned* __restrict__ aux,
                                                            const float* __restrict__ x,
                                                            const float* __restrict__ W,
                                                            unsigned short* __restrict__ hb) {
  __shared__ float lds[D_IN * D_HID + 64 * D_IN];  // 24 KB, shared by both roles
  if (blockIdx.x < NCHUNKS) {
    int* cnt   = reinterpret_cast<int*>(lds);
    int* base_ = cnt + NBUCK;
    int* cur   = base_ + NBUCK;
    for (int i = threadIdx.x; i < NBUCK; i += 256) cnt[i] = 0;
    __syncthreads();
    const int cb = blockIdx.x * CHUNK;
    const int end = (cb + CHUNK < N_EDGES) ? cb + CHUNK : N_EDGES;
    for (int e = cb + threadIdx.x; e < end; e += 256)
      atomicAdd(&cnt[dst[e] / BUCK_NODES], 1);
    __syncthreads();
    for (int i = threadIdx.x; i < NBUCK; i += 256) {
      base_[i] = cnt[i] ? atomicAdd(&gcur[i], cnt[i]) : 0;
      cur[i] = 0;
    }
    __syncthreads();
    for (int e = cb + threadIdx.x; e < end; e += 256) {
      const int d = dst[e];
      const int b = d / BUCK_NODES;
      const int p = base_[b] + atomicAdd(&cur[b], 1);
      if (p < BUCK_REG)  // overflow clamp (statistically never)
        aux[(size_t)b * BUCK_REG + p] =
            ((unsigned)(d - b * BUCK_NODES) << 17) | (unsigned)src[e];
    }
    return;
  }
  // ---- embed role ----
  float* Wl = lds;
  float* xl = lds + D_IN * D_HID;
  for (int i = threadIdx.x; i < D_IN * D_HID; i += 256) Wl[i] = W[i];
  const int base = (blockIdx.x - NCHUNKS) * 64;
  const int nThis = (base + 64 <= N_NODES) ? 64 : (N_NODES - base);
  const float4* x4 = reinterpret_cast<const float4*>(x + (size_t)base * D_IN);
  for (int i = threadIdx.x; i < nThis * (D_IN / 4); i += 256)
    reinterpret_cast<float4*>(xl)[i] = x4[i];
  __syncthreads();
  const int c2 = (threadIdx.x & 63) * 2;
  const int sub = threadIdx.x >> 6;
  for (int r = sub; r < nThis; r += 4) {
    float s0 = 0.f, s1 = 0.f;
    #pragma unroll
    for (int k = 0; k < D_IN; ++k) {
      float xv = xl[r * D_IN + k];
      s0 += xv * Wl[k * D_HID + c2];
      s1 += xv * Wl[k * D_HID + c2 + 1];
    }
    *reinterpret_cast<unsigned*>(hb + (size_t)(base + r) * D_HID + c2) = pack_bf16(s0, s1);
  }
}

// ---------------- combo: CSR sort (0..255) + W pack + graph_off ----------------
// CSR sort writes csr[] directly (scattered 4B stores into a 32KB per-bucket
// region stay L2-resident, ~1x amplification) — no LDS staging, 8+ blocks/CU.
// B-frag for v_mfma_f32_16x16x32_bf16: lane l, elem i = B[kt*32+(l>>4)*8+i][nt*16+(l&15)]
__global__ __launch_bounds__(256) void csr_packw_goff_kernel(const unsigned* __restrict__ aux,
                                                             const int* __restrict__ gcur,
                                                             int* __restrict__ off,
                                                             int* __restrict__ deg,
                                                             int* __restrict__ csr,
                                                             const float* __restrict__ Ws,
                                                             unsigned short* __restrict__ wb_hi,
                                                             const int* __restrict__ batch,
                                                             int* __restrict__ goff) {
  if (blockIdx.x >= NBUCK + PACKW_BLOCKS) {
    const int g = (blockIdx.x - NBUCK - PACKW_BLOCKS) * 256 + threadIdx.x;
    if (g <= N_GRAPHS) {
      int lo = 0, hi = N_NODES;
      while (lo < hi) { int mid = (lo + hi) >> 1; if (batch[mid] < g) lo = mid + 1; else hi = mid; }
      goff[g] = lo;
    }
    return;
  }
  if (blockIdx.x >= NBUCK) {
    const int idx = (blockIdx.x - NBUCK) * 256 + threadIdx.x;
    if (idx < N_LAYERS * 16384) {
      const int layer = idx >> 14;
      const int r = idx & 16383;
      const int t = r >> 9;
      const int lane = (r >> 3) & 63;
      const int i = r & 7;
      const int nt = t >> 2, kt = t & 3;
      const int k = kt * 32 + (lane >> 4) * 8 + i;
      const int c = nt * 16 + (lane & 15);
      wb_hi[idx] = (unsigned short)bf16_rn(Ws[(size_t)layer * 16384 + k * D_HID + c]);
    }
    return;
  }
  __shared__ int sdeg[NBUCK];
  __shared__ int sscan[NBUCK];
  __shared__ int scur[NBUCK];
  const int b = blockIdx.x, t = threadIdx.x;
  const int abase = b * BUCK_REG;
  int cnt = gcur[b]; if (cnt > BUCK_REG) cnt = BUCK_REG;
  const int n0 = b * BUCK_NODES;
  const int nN = (N_NODES - n0 < BUCK_NODES) ? (N_NODES - n0) : BUCK_NODES;
  sdeg[t] = 0;
  __syncthreads();
  for (int i = t; i < cnt; i += 256)
    atomicAdd(&sdeg[aux[(size_t)abase + i] >> 17], 1);
  __syncthreads();
  sscan[t] = sdeg[t];
  __syncthreads();
  #pragma unroll
  for (int d = 1; d < NBUCK; d <<= 1) {
    int v = (t >= d) ? sscan[t - d] : 0;
    __syncthreads();
    sscan[t] += v;
    __syncthreads();
  }
  const int exc_t = sscan[t] - sdeg[t];
  __syncthreads();
  sscan[t] = exc_t;
  scur[t] = 0;
  if (t < nN) { off[n0 + t] = abase + exc_t; deg[n0 + t] = sdeg[t]; }
  __syncthreads();
  for (int i = t; i < cnt; i += 256) {
    const unsigned v = aux[(size_t)abase + i];
    const int d = v >> 17;
    const int pos = sscan[d] + atomicAdd(&scur[d], 1);
    csr[abase + pos] = (int)(v & 0x1ffffu);
  }
}

// ---------------- fused GIN layer + LEADING pool blocks ----------------
// Blocks [0, POOL_BLOCKS): pool hb (this layer's INPUT, stable) — dispatched FIRST
//   so the pool hides under the gather phase (R14 lesson: trailing blocks don't).
// Blocks [POOL_BLOCKS, ...): gather+gemm for 16 nodes (R11-proven gather).
// launch_bounds(256,8): VGPR cap 64 >= measured 40; +33% waves -> more
//   outstanding L2-misses for the BW-bound gather.
__global__ __launch_bounds__(256, 8) void gin_layer_kernel(const unsigned short* __restrict__ hb,
                                                           const int* __restrict__ off,
                                                           const int* __restrict__ degarr,
                                                           const int* __restrict__ csr,
                                                           const unsigned short* __restrict__ wb_hi,
                                                           const float* __restrict__ b,
                                                           unsigned short* __restrict__ hbout,
                                                           const int* __restrict__ goff,
                                                           float* __restrict__ out, int lslice) {
  __shared__ unsigned atile[16 * 64];  // 4 KB, swizzled
  if (blockIdx.x < POOL_BLOCKS) {
    pool_one(hb, goff, out, lslice, blockIdx.x, threadIdx.x);
    return;
  }
  const int wid = threadIdx.x >> 6;
  const int lane = threadIdx.x & 63;
  const int base_m = (blockIdx.x - POOL_BLOCKS) * 16;
  const int q = lane >> 4;
  const int l16 = lane & 15;
  const int r = wid * 4 + q;
  const int node = base_m + r;

  const int e0 = off[node];
  const int deg = degarr[node];

  float s[8];
  {
    const uint4 su = *reinterpret_cast<const uint4*>(hb + (size_t)node * D_HID + l16 * 8);
    const unsigned* sw = reinterpret_cast<const unsigned*>(&su);
    #pragma unroll
    for (int i = 0; i < 4; ++i) {
      s[2 * i]     = 2.f * bf_lo(sw[i]);
      s[2 * i + 1] = 2.f * bf_hi(sw[i]);
    }
  }

  for (int bb = 0; bb < deg; bb += 16) {
    const int vidx = (bb + l16 < deg) ? csr[e0 + bb + l16] : 0;
    #pragma unroll
    for (int half = 0; half < 2; ++half) {
      const int jb = half * 8;
      if (bb + jb < deg) {                 // quarter-uniform branch
        uint4 u[8];
        #pragma unroll
        for (int j = 0; j < 8; ++j) {
          const int idx = __shfl(vidx, (lane & 48) + jb + j, 64);
          u[j] = *reinterpret_cast<const uint4*>(hb + (size_t)idx * D_HID + l16 * 8);
        }
        const int rem = deg - bb - jb;
        #pragma unroll
        for (int j = 0; j < 8; ++j) {
          const float sc = (j < rem) ? 1.f : 0.f;
          const unsigned* uw = reinterpret_cast<const unsigned*>(&u[j]);
          #pragma unroll
          for (int i = 0; i < 4; ++i) {
            s[2 * i]     += sc * bf_lo(uw[i]);
            s[2 * i + 1] += sc * bf_hi(uw[i]);
          }
        }
      }
    }
  }

  {
    uint4 pk;
    unsigned* pw = reinterpret_cast<unsigned*>(&pk);
    #pragma unroll
    for (int i = 0; i < 4; ++i) pw[i] = pack_bf16(s[2 * i], s[2 * i + 1]);
    const int wbase = (l16 * 4) ^ ((r & 7) << 2);
    *reinterpret_cast<uint4*>(&atile[r * 64 + wbase]) = pk;
  }
  __syncthreads();

  const int l15 = lane & 15;
  const int lg = lane >> 4;
  bf16x8 a[4];
  #pragma unroll
  for (int kt = 0; kt < 4; ++kt) {
    const int u32off = l15 * 64 + ((kt * 16 + lg * 4) ^ ((l15 & 7) << 2));
    a[kt] = *reinterpret_cast<const bf16x8*>(&atile[u32off]);
  }
  #pragma unroll
  for (int qq = 0; qq < 2; ++qq) {
    const int nt = wid * 2 + qq;
    f32x4 acc = {0.f, 0.f, 0.f, 0.f};
    #pragma unroll
    for (int kt = 0; kt < 4; ++kt) {
      const int toff = (nt * 4 + kt) * 512 + lane * 8;
      bf16x8 bh = *reinterpret_cast<const bf16x8*>(wb_hi + toff);
      acc = __builtin_amdgcn_mfma_f32_16x16x32_bf16(a[kt], bh, acc, 0, 0, 0);
    }
    const int col = nt * 16 + l15;
    const float bcol = b[col];
    #pragma unroll
    for (int i = 0; i < 4; ++i) {
      const int onode = base_m + lg * 4 + i;
      hbout[(size_t)onode * D_HID + col] = (unsigned short)bf16_rn(acc[i] + bcol);
    }
  }
}

// final pool of the last feature buffer (hb[5])
__global__ __launch_bounds__(256) void pool_last_kernel(const unsigned short* __restrict__ h,
                                                        const int* __restrict__ goff,
                                                        float* __restrict__ out) {
  pool_one(h, goff, out, N_LAYERS * D_HID, blockIdx.x, threadIdx.x);
}

// ---------------- launch ----------------

extern "C" void kernel_launch(void* const* d_in, const int* in_sizes, int n_in,
                              void* d_out, int out_size, void* d_ws, size_t ws_size,
                              hipStream_t stream) {
  const float* x       = (const float*)d_in[0];
  const int*   edges   = (const int*)d_in[1];
  const int*   src     = edges;
  const int*   dst     = edges + N_EDGES;
  const int*   batch   = (const int*)d_in[2];
  const float* W_embed = (const float*)d_in[3];
  const float* Ws      = (const float*)d_in[4];
  const float* bs      = (const float*)d_in[5];
  float* out = (float*)d_out;

  const size_t HSZ = (size_t)N_NODES * D_HID;
  unsigned short* hb[N_LAYERS + 1];
  hb[0] = (unsigned short*)d_ws;
  for (int l = 1; l <= N_LAYERS; ++l) hb[l] = hb[l - 1] + HSZ;
  unsigned short* wb_hi = hb[N_LAYERS] + HSZ;                 // 5*16384 bf16
  unsigned* aux = (unsigned*)(wb_hi + (size_t)N_LAYERS * 16384); // 256*8192 u32
  int* csr  = (int*)(aux + (size_t)NBUCK * BUCK_REG);         // 256*8192 int
  int* off  = csr + (size_t)NBUCK * BUCK_REG;                 // N
  int* deg  = off + N_NODES;                                  // N
  int* gcur = deg + N_NODES;                                  // 256
  int* goff = gcur + NBUCK;                                   // G+1

  // zero bucket cursors (replay-safe)
  hipMemsetAsync(gcur, 0, NBUCK * sizeof(int), stream);

  // fused: edge scatter (blocks 0..195) + embedding (remaining blocks)
  scatter_embed_kernel<<<NCHUNKS + EMBED_BLOCKS, 256, 0, stream>>>(
      src, dst, gcur, aux, x, W_embed, hb[0]);

  // combo: per-bucket CSR sort + W pack + graph offsets
  csr_packw_goff_kernel<<<NBUCK + PACKW_BLOCKS + GOFF_BLOCKS, 256, 0, stream>>>(
      aux, gcur, off, deg, csr, Ws, wb_hi, batch, goff);

  // fused gather+gemm layers; layer l also pools its input feature hb[l]
  // (pool blocks FIRST so they hide under the gather phase)
  for (int l = 0; l < N_LAYERS; ++l) {
    gin_layer_kernel<<<POOL_BLOCKS + NM_BLOCKS, 256, 0, stream>>>(
        hb[l], off, deg, csr,
        wb_hi + (size_t)l * 16384,
        bs + (size_t)l * D_HID, hb[l + 1],
        goff, out, l * D_HID);
  }

  // pool the final feature
  pool_last_kernel<<<POOL_BLOCKS, 256, 0, stream>>>(hb[N_LAYERS], goff, out);
}

// Round 18
// 218.187 us; speedup vs baseline: 1.0379x; 1.0379x over previous
//
#include <hip/hip_runtime.h>

#define N_NODES 50000
#define N_EDGES 800000
#define N_GRAPHS 1024
#define N_LAYERS 5
#define D_IN 32
#define D_HID 128

#define NBUCK 256
#define BUCK_NODES 196   // ceil(N_NODES/NBUCK)
#define BUCK_REG 8192    // padded slots per bucket (mean ~3125, clamp-guarded)
#define CHUNK 4096
#define NCHUNKS ((N_EDGES + CHUNK - 1) / CHUNK)   // 196
#define EMBED_BLOCKS ((N_NODES + 63) / 64)        // 782
#define PACKW_BLOCKS ((N_LAYERS * 16384 + 255) / 256)  // 320
#define GOFF_BLOCKS ((N_GRAPHS + 1 + 255) / 256)  // 5
#define NM_BLOCKS (N_NODES / 16)                  // 3125
#define POOL_BLOCKS (N_GRAPHS / 8)                // 128

typedef __attribute__((ext_vector_type(8))) short bf16x8;
typedef __attribute__((ext_vector_type(4))) float f32x4;

// ---------------- bf16 helpers ----------------

__device__ __forceinline__ float bf_lo(unsigned u) { return __uint_as_float(u << 16); }
__device__ __forceinline__ float bf_hi(unsigned u) { return __uint_as_float(u & 0xffff0000u); }
__device__ __forceinline__ unsigned bf16_rn(float f) {
  unsigned u = __float_as_uint(f);
  return (u + 0x7fffu + ((u >> 16) & 1u)) >> 16;  // round-to-nearest-even
}
__device__ __forceinline__ unsigned pack_bf16(float a, float b) {
  return bf16_rn(a) | (bf16_rn(b) << 16);
}

// single-feature graph pool: 8 graphs/block, 32 threads/graph (4 cols each)
__device__ __forceinline__ void pool_one(const unsigned short* __restrict__ h,
                                         const int* __restrict__ goff,
                                         float* __restrict__ out,
                                         int lslice, int pb, int tid) {
  const int g = pb * 8 + (tid >> 5);
  const int t = tid & 31;
  if (g >= N_GRAPHS) return;
  const int n0 = goff[g], n1 = goff[g + 1];
  float4 s = {0.f, 0.f, 0.f, 0.f};
  int n = n0;
  for (; n + 1 < n1; n += 2) {
    uint2 v = *reinterpret_cast<const uint2*>(h + (size_t)n * D_HID + t * 4);
    uint2 w = *reinterpret_cast<const uint2*>(h + (size_t)(n + 1) * D_HID + t * 4);
    s.x += bf_lo(v.x) + bf_lo(w.x); s.y += bf_hi(v.x) + bf_hi(w.x);
    s.z += bf_lo(v.y) + bf_lo(w.y); s.w += bf_hi(v.y) + bf_hi(w.y);
  }
  if (n < n1) {
    uint2 v = *reinterpret_cast<const uint2*>(h + (size_t)n * D_HID + t * 4);
    s.x += bf_lo(v.x); s.y += bf_hi(v.x); s.z += bf_lo(v.y); s.w += bf_hi(v.y);
  }
  *reinterpret_cast<float4*>(out + (size_t)g * ((N_LAYERS + 1) * D_HID) + lslice + t * 4) = s;
}

// ---------------- fused: bucket scatter (blocks 0..NCHUNKS-1) + embed (rest) ----------------
// aux entry: (dst_local << 17) | src  (dst_local < 196 < 2^8, src < 50000 < 2^17)

__global__ __launch_bounds__(256) void scatter_embed_kernel(const int* __restrict__ src,
                                                            const int* __restrict__ dst,
                                                            int* __restrict__ gcur,
                                                            unsigned* __restrict__ aux,
                                                            const float* __restrict__ x,
                                                            const float* __restrict__ W,
                                                            unsigned short* __restrict__ hb) {
  __shared__ float lds[D_IN * D_HID + 64 * D_IN];  // 24 KB, shared by both roles
  if (blockIdx.x < NCHUNKS) {
    int* cnt   = reinterpret_cast<int*>(lds);
    int* base_ = cnt + NBUCK;
    int* cur   = base_ + NBUCK;
    for (int i = threadIdx.x; i < NBUCK; i += 256) cnt[i] = 0;
    __syncthreads();
    const int cb = blockIdx.x * CHUNK;
    const int end = (cb + CHUNK < N_EDGES) ? cb + CHUNK : N_EDGES;
    for (int e = cb + threadIdx.x; e < end; e += 256)
      atomicAdd(&cnt[dst[e] / BUCK_NODES], 1);
    __syncthreads();
    for (int i = threadIdx.x; i < NBUCK; i += 256) {
      base_[i] = cnt[i] ? atomicAdd(&gcur[i], cnt[i]) : 0;
      cur[i] = 0;
    }
    __syncthreads();
    for (int e = cb + threadIdx.x; e < end; e += 256) {
      const int d = dst[e];
      const int b = d / BUCK_NODES;
      const int p = base_[b] + atomicAdd(&cur[b], 1);
      if (p < BUCK_REG)  // overflow clamp (statistically never)
        aux[(size_t)b * BUCK_REG + p] =
            ((unsigned)(d - b * BUCK_NODES) << 17) | (unsigned)src[e];
    }
    return;
  }
  // ---- embed role ----
  float* Wl = lds;
  float* xl = lds + D_IN * D_HID;
  for (int i = threadIdx.x; i < D_IN * D_HID; i += 256) Wl[i] = W[i];
  const int base = (blockIdx.x - NCHUNKS) * 64;
  const int nThis = (base + 64 <= N_NODES) ? 64 : (N_NODES - base);
  const float4* x4 = reinterpret_cast<const float4*>(x + (size_t)base * D_IN);
  for (int i = threadIdx.x; i < nThis * (D_IN / 4); i += 256)
    reinterpret_cast<float4*>(xl)[i] = x4[i];
  __syncthreads();
  const int c2 = (threadIdx.x & 63) * 2;
  const int sub = threadIdx.x >> 6;
  for (int r = sub; r < nThis; r += 4) {
    float s0 = 0.f, s1 = 0.f;
    #pragma unroll
    for (int k = 0; k < D_IN; ++k) {
      float xv = xl[r * D_IN + k];
      s0 += xv * Wl[k * D_HID + c2];
      s1 += xv * Wl[k * D_HID + c2 + 1];
    }
    *reinterpret_cast<unsigned*>(hb + (size_t)(base + r) * D_HID + c2) = pack_bf16(s0, s1);
  }
}

// ---------------- combo: CSR sort (0..255) + W pack + graph_off ----------------
// B-frag for v_mfma_f32_16x16x32_bf16: lane l, elem i = B[kt*32+(l>>4)*8+i][nt*16+(l&15)]
// Single-bf16 weights (wb_lo dropped: halves gemm MFMA count + B-tile L2 traffic).
__global__ __launch_bounds__(256) void csr_packw_goff_kernel(const unsigned* __restrict__ aux,
                                                             const int* __restrict__ gcur,
                                                             int* __restrict__ off,
                                                             int* __restrict__ deg,
                                                             int* __restrict__ csr,
                                                             const float* __restrict__ Ws,
                                                             unsigned short* __restrict__ wb_hi,
                                                             const int* __restrict__ batch,
                                                             int* __restrict__ goff) {
  if (blockIdx.x >= NBUCK + PACKW_BLOCKS) {
    const int g = (blockIdx.x - NBUCK - PACKW_BLOCKS) * 256 + threadIdx.x;
    if (g <= N_GRAPHS) {
      int lo = 0, hi = N_NODES;
      while (lo < hi) { int mid = (lo + hi) >> 1; if (batch[mid] < g) lo = mid + 1; else hi = mid; }
      goff[g] = lo;
    }
    return;
  }
  if (blockIdx.x >= NBUCK) {
    const int idx = (blockIdx.x - NBUCK) * 256 + threadIdx.x;
    if (idx < N_LAYERS * 16384) {
      const int layer = idx >> 14;
      const int r = idx & 16383;
      const int t = r >> 9;
      const int lane = (r >> 3) & 63;
      const int i = r & 7;
      const int nt = t >> 2, kt = t & 3;
      const int k = kt * 32 + (lane >> 4) * 8 + i;
      const int c = nt * 16 + (lane & 15);
      wb_hi[idx] = (unsigned short)bf16_rn(Ws[(size_t)layer * 16384 + k * D_HID + c]);
    }
    return;
  }
  __shared__ int sdeg[NBUCK];
  __shared__ int sscan[NBUCK];
  __shared__ int scur[NBUCK];
  __shared__ int lcsr[BUCK_REG];  // 32 KB
  const int b = blockIdx.x, t = threadIdx.x;
  const int abase = b * BUCK_REG;
  int cnt = gcur[b]; if (cnt > BUCK_REG) cnt = BUCK_REG;
  const int n0 = b * BUCK_NODES;
  const int nN = (N_NODES - n0 < BUCK_NODES) ? (N_NODES - n0) : BUCK_NODES;
  sdeg[t] = 0;
  __syncthreads();
  for (int i = t; i < cnt; i += 256)
    atomicAdd(&sdeg[aux[(size_t)abase + i] >> 17], 1);
  __syncthreads();
  sscan[t] = sdeg[t];
  __syncthreads();
  #pragma unroll
  for (int d = 1; d < NBUCK; d <<= 1) {
    int v = (t >= d) ? sscan[t - d] : 0;
    __syncthreads();
    sscan[t] += v;
    __syncthreads();
  }
  const int exc_t = sscan[t] - sdeg[t];
  __syncthreads();
  sscan[t] = exc_t;
  scur[t] = 0;
  if (t < nN) { off[n0 + t] = abase + exc_t; deg[n0 + t] = sdeg[t]; }
  __syncthreads();
  for (int i = t; i < cnt; i += 256) {
    const unsigned v = aux[(size_t)abase + i];
    const int d = v >> 17;
    const int pos = sscan[d] + atomicAdd(&scur[d], 1);
    lcsr[pos] = (int)(v & 0x1ffffu);
  }
  __syncthreads();
  for (int i = t; i < cnt; i += 256) csr[abase + i] = lcsr[i];
}

// ---------------- fused GIN layer + LEADING pool blocks ----------------
// Blocks [0, POOL_BLOCKS): pool hb (this layer's INPUT, stable) — dispatched FIRST
//   so the pool hides under the gather phase (R14 lesson: trailing blocks don't).
// Blocks [POOL_BLOCKS, ...): gather+gemm for 16 nodes (R11-proven gather).
__global__ __launch_bounds__(256, 6) void gin_layer_kernel(const unsigned short* __restrict__ hb,
                                                           const int* __restrict__ off,
                                                           const int* __restrict__ degarr,
                                                           const int* __restrict__ csr,
                                                           const unsigned short* __restrict__ wb_hi,
                                                           const float* __restrict__ b,
                                                           unsigned short* __restrict__ hbout,
                                                           const int* __restrict__ goff,
                                                           float* __restrict__ out, int lslice) {
  __shared__ unsigned atile[16 * 64];  // 4 KB, swizzled
  if (blockIdx.x < POOL_BLOCKS) {
    pool_one(hb, goff, out, lslice, blockIdx.x, threadIdx.x);
    return;
  }
  const int wid = threadIdx.x >> 6;
  const int lane = threadIdx.x & 63;
  const int base_m = (blockIdx.x - POOL_BLOCKS) * 16;
  const int q = lane >> 4;
  const int l16 = lane & 15;
  const int r = wid * 4 + q;
  const int node = base_m + r;

  const int e0 = off[node];
  const int deg = degarr[node];

  float s[8];
  {
    const uint4 su = *reinterpret_cast<const uint4*>(hb + (size_t)node * D_HID + l16 * 8);
    const unsigned* sw = reinterpret_cast<const unsigned*>(&su);
    #pragma unroll
    for (int i = 0; i < 4; ++i) {
      s[2 * i]     = 2.f * bf_lo(sw[i]);
      s[2 * i + 1] = 2.f * bf_hi(sw[i]);
    }
  }

  for (int bb = 0; bb < deg; bb += 16) {
    const int vidx = (bb + l16 < deg) ? csr[e0 + bb + l16] : 0;
    #pragma unroll
    for (int half = 0; half < 2; ++half) {
      const int jb = half * 8;
      if (bb + jb < deg) {                 // quarter-uniform branch
        uint4 u[8];
        #pragma unroll
        for (int j = 0; j < 8; ++j) {
          const int idx = __shfl(vidx, (lane & 48) + jb + j, 64);
          u[j] = *reinterpret_cast<const uint4*>(hb + (size_t)idx * D_HID + l16 * 8);
        }
        const int rem = deg - bb - jb;
        #pragma unroll
        for (int j = 0; j < 8; ++j) {
          const float sc = (j < rem) ? 1.f : 0.f;
          const unsigned* uw = reinterpret_cast<const unsigned*>(&u[j]);
          #pragma unroll
          for (int i = 0; i < 4; ++i) {
            s[2 * i]     += sc * bf_lo(uw[i]);
            s[2 * i + 1] += sc * bf_hi(uw[i]);
          }
        }
      }
    }
  }

  {
    uint4 pk;
    unsigned* pw = reinterpret_cast<unsigned*>(&pk);
    #pragma unroll
    for (int i = 0; i < 4; ++i) pw[i] = pack_bf16(s[2 * i], s[2 * i + 1]);
    const int wbase = (l16 * 4) ^ ((r & 7) << 2);
    *reinterpret_cast<uint4*>(&atile[r * 64 + wbase]) = pk;
  }
  __syncthreads();

  const int l15 = lane & 15;
  const int lg = lane >> 4;
  bf16x8 a[4];
  #pragma unroll
  for (int kt = 0; kt < 4; ++kt) {
    const int u32off = l15 * 64 + ((kt * 16 + lg * 4) ^ ((l15 & 7) << 2));
    a[kt] = *reinterpret_cast<const bf16x8*>(&atile[u32off]);
  }
  #pragma unroll
  for (int qq = 0; qq < 2; ++qq) {
    const int nt = wid * 2 + qq;
    f32x4 acc = {0.f, 0.f, 0.f, 0.f};
    #pragma unroll
    for (int kt = 0; kt < 4; ++kt) {
      const int toff = (nt * 4 + kt) * 512 + lane * 8;
      bf16x8 bh = *reinterpret_cast<const bf16x8*>(wb_hi + toff);
      acc = __builtin_amdgcn_mfma_f32_16x16x32_bf16(a[kt], bh, acc, 0, 0, 0);
    }
    const int col = nt * 16 + l15;
    const float bcol = b[col];
    #pragma unroll
    for (int i = 0; i < 4; ++i) {
      const int onode = base_m + lg * 4 + i;
      hbout[(size_t)onode * D_HID + col] = (unsigned short)bf16_rn(acc[i] + bcol);
    }
  }
}

// final pool of the last feature buffer (hb[5])
__global__ __launch_bounds__(256) void pool_last_kernel(const unsigned short* __restrict__ h,
                                                        const int* __restrict__ goff,
                                                        float* __restrict__ out) {
  pool_one(h, goff, out, N_LAYERS * D_HID, blockIdx.x, threadIdx.x);
}

// ---------------- launch ----------------

extern "C" void kernel_launch(void* const* d_in, const int* in_sizes, int n_in,
                              void* d_out, int out_size, void* d_ws, size_t ws_size,
                              hipStream_t stream) {
  const float* x       = (const float*)d_in[0];
  const int*   edges   = (const int*)d_in[1];
  const int*   src     = edges;
  const int*   dst     = edges + N_EDGES;
  const int*   batch   = (const int*)d_in[2];
  const float* W_embed = (const float*)d_in[3];
  const float* Ws      = (const float*)d_in[4];
  const float* bs      = (const float*)d_in[5];
  float* out = (float*)d_out;

  const size_t HSZ = (size_t)N_NODES * D_HID;
  unsigned short* hb[N_LAYERS + 1];
  hb[0] = (unsigned short*)d_ws;
  for (int l = 1; l <= N_LAYERS; ++l) hb[l] = hb[l - 1] + HSZ;
  unsigned short* wb_hi = hb[N_LAYERS] + HSZ;                 // 5*16384 bf16
  unsigned* aux = (unsigned*)(wb_hi + (size_t)N_LAYERS * 16384); // 256*8192 u32
  int* csr  = (int*)(aux + (size_t)NBUCK * BUCK_REG);         // 256*8192 int
  int* off  = csr + (size_t)NBUCK * BUCK_REG;                 // N
  int* deg  = off + N_NODES;                                  // N
  int* gcur = deg + N_NODES;                                  // 256
  int* goff = gcur + NBUCK;                                   // G+1

  // zero bucket cursors (replay-safe)
  hipMemsetAsync(gcur, 0, NBUCK * sizeof(int), stream);

  // fused: edge scatter (blocks 0..195) + embedding (remaining blocks)
  scatter_embed_kernel<<<NCHUNKS + EMBED_BLOCKS, 256, 0, stream>>>(
      src, dst, gcur, aux, x, W_embed, hb[0]);

  // combo: per-bucket CSR sort + W pack + graph offsets
  csr_packw_goff_kernel<<<NBUCK + PACKW_BLOCKS + GOFF_BLOCKS, 256, 0, stream>>>(
      aux, gcur, off, deg, csr, Ws, wb_hi, batch, goff);

  // fused gather+gemm layers; layer l also pools its input feature hb[l]
  // (pool blocks FIRST so they hide under the gather phase)
  for (int l = 0; l < N_LAYERS; ++l) {
    gin_layer_kernel<<<POOL_BLOCKS + NM_BLOCKS, 256, 0, stream>>>(
        hb[l], off, deg, csr,
        wb_hi + (size_t)l * 16384,
        bs + (size_t)l * D_HID, hb[l + 1],
        goff, out, l * D_HID);
  }

  // pool the final feature
  pool_last_kernel<<<POOL_BLOCKS, 256, 0, stream>>>(hb[N_LAYERS], goff, out);
}